// Round 5
// baseline (277.862 us; speedup 1.0000x reference)
//
#include <hip/hip_runtime.h>
#include <hip/hip_bf16.h>

// ---------- helpers ----------
typedef __bf16 bf16x8 __attribute__((ext_vector_type(8)));
typedef float f32x4 __attribute__((ext_vector_type(4)));
typedef unsigned short u16x8 __attribute__((ext_vector_type(8)));

__device__ __forceinline__ unsigned short f2bf(float f) {
  unsigned u = __float_as_uint(f);
  u += 0x7FFF + ((u >> 16) & 1);          // RNE
  return (unsigned short)(u >> 16);
}
__device__ __forceinline__ float bf2f(unsigned short h) {
  return __uint_as_float((unsigned)h << 16);
}

__device__ __forceinline__ void gload_lds16(const void* g, void* l) {
  __builtin_amdgcn_global_load_lds(
      (const __attribute__((address_space(1))) void*)g,
      (__attribute__((address_space(3))) void*)l, 16, 0, 0);
}

// grid-strided fp32->bf16 convert slice, run by tail blocks of latency-bound launches
__device__ __forceinline__ void convert_slice(const float* __restrict__ x,
                                              unsigned short* __restrict__ xb,
                                              int base8, int cnt8, int cb, int nb)
{
  int i = cb * 256 + (int)threadIdx.x;
  const int stride = nb * 256;
  for (; i < cnt8; i += stride) {
    const size_t g = (size_t)(base8 + i);
    float4 v0 = ((const float4*)x)[2 * g];
    float4 v1 = ((const float4*)x)[2 * g + 1];
    u16x8 uv;
    uv[0] = f2bf(v0.x); uv[1] = f2bf(v0.y); uv[2] = f2bf(v0.z); uv[3] = f2bf(v0.w);
    uv[4] = f2bf(v1.x); uv[5] = f2bf(v1.y); uv[6] = f2bf(v1.z); uv[7] = f2bf(v1.w);
    ((u16x8*)xb)[g] = uv;
  }
}

// ---------- 1) row softmax of 4 P matrices -> bf16 (+ convert tail blocks) ----------
__global__ __launch_bounds__(256)
void softmax4_kernel(const float* __restrict__ P0, const float* __restrict__ P1,
                     const float* __restrict__ P2, const float* __restrict__ P3,
                     unsigned short* __restrict__ S,
                     const float* __restrict__ cvx, unsigned short* __restrict__ cvxb,
                     int cvt_cnt)
{
  if (blockIdx.x >= 4096) {
    convert_slice(cvx, cvxb, 0, cvt_cnt, blockIdx.x - 4096, gridDim.x - 4096);
    return;
  }
  const int bid = blockIdx.x;
  const int mat = bid >> 10, row = bid & 1023;
  const float* P = (mat == 0 ? P0 : mat == 1 ? P1 : mat == 2 ? P2 : P3) + (size_t)row * 1024;
  unsigned short* out = S + ((size_t)mat << 20) + (size_t)row * 1024;
  const int t = threadIdx.x, w = t >> 6, l = t & 63;
  float4 v = ((const float4*)P)[t];
  float mx = fmaxf(fmaxf(v.x, v.y), fmaxf(v.z, v.w));
  #pragma unroll
  for (int off = 32; off > 0; off >>= 1) mx = fmaxf(mx, __shfl_xor(mx, off));
  __shared__ float redA[4], redB[4];
  if (l == 0) redA[w] = mx;
  __syncthreads();
  mx = fmaxf(fmaxf(redA[0], redA[1]), fmaxf(redA[2], redA[3]));
  float e0 = __expf(v.x - mx), e1 = __expf(v.y - mx);
  float e2 = __expf(v.z - mx), e3 = __expf(v.w - mx);
  float s = e0 + e1 + e2 + e3;
  #pragma unroll
  for (int off = 32; off > 0; off >>= 1) s += __shfl_xor(s, off);
  if (l == 0) redB[w] = s;
  __syncthreads();
  s = redB[0] + redB[1] + redB[2] + redB[3];
  float inv = 1.0f / s;
  ushort4 o;
  o.x = f2bf(e0 * inv); o.y = f2bf(e1 * inv);
  o.z = f2bf(e2 * inv); o.w = f2bf(e3 * inv);
  ((ushort4*)out)[t] = o;
}

// ---------- 2) out^T = (blockdiag(K)^T @ in)^T  (+ convert tail blocks) ----------
__global__ __launch_bounds__(256)
void blockdiagT_kernel(const float* __restrict__ Kb, const unsigned short* __restrict__ in,
                       unsigned short* __restrict__ outT,
                       const float* __restrict__ cvx, unsigned short* __restrict__ cvxb,
                       int cvt_base, int cvt_cnt)
{
  if (blockIdx.x >= 128) {
    convert_slice(cvx, cvxb, cvt_base, cvt_cnt, blockIdx.x - 128, gridDim.x - 128);
    return;
  }
  const int n = blockIdx.x >> 2;
  const int c = (blockIdx.x & 3) * 256 + threadIdx.x;
  __shared__ float Ks[32][33];
  for (int t = threadIdx.x; t < 1024; t += 256)
    Ks[t >> 5][t & 31] = Kb[n * 1024 + t];
  __syncthreads();
  float ri[32];
  #pragma unroll
  for (int i = 0; i < 32; ++i)
    ri[i] = bf2f(in[(size_t)(n * 32 + i) * 1024 + c]);
  unsigned short ov[32];
  #pragma unroll
  for (int o = 0; o < 32; ++o) {
    float acc = 0.f;
    #pragma unroll
    for (int i = 0; i < 32; ++i) acc = fmaf(Ks[i][o], ri[i], acc);
    ov[o] = f2bf(acc);
  }
  u16x8* dst = (u16x8*)(outT + (size_t)c * 1024 + n * 32);
  const u16x8* src = (const u16x8*)ov;
  #pragma unroll
  for (int q = 0; q < 4; ++q) dst[q] = src[q];
}

// ---------- 3a) 2-barrier GEMM (compose chain + fallback): C = A @ B^T ----------
template<int TILE, bool A_FP32, bool OUT_BIAS>
__global__ __launch_bounds__(256)
void gemm_bt_kernel(const void* __restrict__ Av, const unsigned short* __restrict__ B,
                    void* __restrict__ Cv, const float* __restrict__ bias,
                    int M, int N, int K, int nprim,
                    const float* cvx, unsigned short* cvxb, int cvt_base, int cvt_cnt)
{
  if ((int)blockIdx.x >= nprim) {
    convert_slice(cvx, cvxb, cvt_base, cvt_cnt, blockIdx.x - nprim, gridDim.x - nprim);
    return;
  }
  constexpr int FR  = TILE / 32;
  constexpr int SIT = TILE / 32;
  __shared__ unsigned short Asm[TILE * 64];
  __shared__ unsigned short Bsm[TILE * 64];
  const int tid = threadIdx.x;
  const int w = tid >> 6, l = tid & 63;
  const int bid = blockIdx.x;
  const int cpx = nprim >> 3;
  const int swz = (bid & 7) * cpx + (bid >> 3);
  const int ntn = N / TILE;
  const int n0 = (swz % ntn) * TILE;
  const int m0 = (swz / ntn) * TILE;
  const int wr = (w >> 1) * (TILE / 2), wc = (w & 1) * (TILE / 2);
  const int lr = l & 15, kg = (l >> 4) << 3;

  f32x4 acc[FR][FR] = {};
  const int KT = K >> 6;
  for (int kt = 0; kt < KT; ++kt) {
    const int k0 = kt << 6;
    if (kt) __syncthreads();
    #pragma unroll
    for (int it = 0; it < SIT; ++it) {
      int li = it * 256 + tid;
      int row = li >> 3, c8 = (li & 7) << 3;
      const unsigned short* g = B + (size_t)(n0 + row) * K + (k0 + c8);
      gload_lds16(g, (char*)Bsm + it * 4096 + w * 1024);
    }
    if (A_FP32) {
      const float* Af = (const float*)Av;
      #pragma unroll
      for (int p = 0; p < SIT; ++p) {
        int row = (tid >> 3) + p * 32;
        int c8 = (tid & 7) << 3;
        const float* g = Af + (size_t)(m0 + row) * K + (k0 + c8);
        float4 v0 = ((const float4*)g)[0];
        float4 v1 = ((const float4*)g)[1];
        u16x8 uv;
        uv[0] = f2bf(v0.x); uv[1] = f2bf(v0.y); uv[2] = f2bf(v0.z); uv[3] = f2bf(v0.w);
        uv[4] = f2bf(v1.x); uv[5] = f2bf(v1.y); uv[6] = f2bf(v1.z); uv[7] = f2bf(v1.w);
        *(u16x8*)&Asm[row * 64 + c8] = uv;
      }
    } else {
      const unsigned short* Ab = (const unsigned short*)Av;
      #pragma unroll
      for (int it = 0; it < SIT; ++it) {
        int li = it * 256 + tid;
        int row = li >> 3, c8 = (li & 7) << 3;
        const unsigned short* g = Ab + (size_t)(m0 + row) * K + (k0 + c8);
        gload_lds16(g, (char*)Asm + it * 4096 + w * 1024);
      }
    }
    __syncthreads();
    #pragma unroll
    for (int ks = 0; ks < 2; ++ks) {
      const int kb = ks * 32 + kg;
      bf16x8 af[FR], bfr[FR];
      #pragma unroll
      for (int i = 0; i < FR; ++i)
        af[i] = *(const bf16x8*)&Asm[(wr + i * 16 + lr) * 64 + kb];
      #pragma unroll
      for (int j = 0; j < FR; ++j)
        bfr[j] = *(const bf16x8*)&Bsm[(wc + j * 16 + lr) * 64 + kb];
      #pragma unroll
      for (int i = 0; i < FR; ++i)
        #pragma unroll
        for (int j = 0; j < FR; ++j)
          acc[i][j] = __builtin_amdgcn_mfma_f32_16x16x32_bf16(af[i], bfr[j], acc[i][j], 0, 0, 0);
    }
  }
  const int cr = (l >> 4) << 2;
  const int cc = l & 15;
  if (OUT_BIAS) {
    float* C = (float*)Cv;
    #pragma unroll
    for (int j = 0; j < FR; ++j) {
      int col = n0 + wc + j * 16 + cc;
      float bv = bias[col];
      #pragma unroll
      for (int i = 0; i < FR; ++i) {
        int rbase = m0 + wr + i * 16 + cr;
        #pragma unroll
        for (int r = 0; r < 4; ++r)
          C[(size_t)(rbase + r) * N + col] = acc[i][j][r] + bv;
      }
    }
  } else {
    unsigned short* C = (unsigned short*)Cv;
    #pragma unroll
    for (int j = 0; j < FR; ++j) {
      int col = n0 + wc + j * 16 + cc;
      #pragma unroll
      for (int i = 0; i < FR; ++i) {
        int rbase = m0 + wr + i * 16 + cr;
        #pragma unroll
        for (int r = 0; r < 4; ++r)
          C[(size_t)(rbase + r) * N + col] = f2bf(acc[i][j][r]);
      }
    }
  }
}

// ---------- 3b) 256x256 phase-pipelined GEMM (final): C = A @ B^T + bias ----------
// 8 waves (wm=w>>2 in {0,1}, wn=w&3); wave tile rows wm*128+[0,128), cols wn*64+[0,64).
// Each wave reads ONLY A-half wm and B-half wn>>1. Per K-tile 4 phases, each phase
// computes one 64x32 quadrant (QI,QJ) over full K=64 (16 MFMA 16x16x32).
// Phase = {12 ds_read (pre-barrier) | stage -> s_barrier -> lgkmcnt(0) ->
//          setprio(1) 16 MFMA setprio(0) -> s_barrier}  [m201 template]
// Staging: exactly 1 K-tile ahead into the other buffer (race-free); all 8 loads
// issued by phase 1; single vmcnt(0)+barrier at tile end (~2.5 phases after issue).
// 2 m-tiles per block (grid 256 = one full-GPU round). XOR swizzle byte^=(row&7)<<4,
// conflict-free for the 16-row fragment reads (verified round 3: 0 conflicts).
__device__ __forceinline__ void write_c256(const f32x4 (&acc)[2][2][4][2],
    float* __restrict__ C, const float* __restrict__ bias,
    int mbase, int n0, int N, int wm, int wn, int l)
{
  const int cr = (l >> 4) << 2;
  const int cc = l & 15;
  #pragma unroll
  for (int qi = 0; qi < 2; ++qi)
    #pragma unroll
    for (int qj = 0; qj < 2; ++qj)
      #pragma unroll
      for (int j = 0; j < 2; ++j) {
        const int col = n0 + wn * 64 + qj * 32 + j * 16 + cc;
        const float bv = bias[col];
        #pragma unroll
        for (int i = 0; i < 4; ++i) {
          const int rbase = mbase + wm * 128 + qi * 64 + i * 16 + cr;
          #pragma unroll
          for (int r = 0; r < 4; ++r)
            C[(size_t)(rbase + r) * N + col] = acc[qi][qj][i][j][r] + bv;
        }
      }
}

__global__ __launch_bounds__(512, 2)
void gemm256_kernel(const unsigned short* __restrict__ A,   // [M,K] bf16
                    const unsigned short* __restrict__ B,   // [N,K] bf16
                    float* __restrict__ C, const float* __restrict__ bias,
                    int N, int K)
{
  extern __shared__ __align__(16) char lds[];   // 131072 B
  const int tid = threadIdx.x;
  const int w = tid >> 6, l = tid & 63;
  const int wm = w >> 2, wn = w & 3;
  const int lr = l & 15;
  const int kg16 = (l >> 4) << 4;     // byte offset of lane's 16B within 64B k-step
  const int swl = (l & 7) << 4;       // read-side XOR swizzle ((row&7)<<4, row%8==l%8)
  const int brow = (wn & 1) * 64;     // B row base within its half

  const int nwg = gridDim.x;
  const int bid = blockIdx.x;
  const int cpx = nwg >> 3;
  const int swz = (bid & 7) * cpx + (bid >> 3);
  const int ntn = N >> 8;
  const int n0 = (swz % ntn) << 8;
  const int m0 = (swz / ntn) << 9;    // 512 rows (2 m-tiles) per block

  // staging source offsets (elements), inverse-swizzled global col
  unsigned int aoff[2][2], boff[2][2];
  #pragma unroll
  for (int q = 0; q < 2; ++q)
    #pragma unroll
    for (int it = 0; it < 2; ++it) {
      int L = it * 8192 + tid * 16;            // byte pos within 16KB half
      int r = L >> 7;                          // row 0..127
      int cs = (L & 127) ^ ((r & 7) << 4);     // pre-swizzled source col bytes
      aoff[q][it] = (unsigned)(m0 + q * 128 + r) * K + (cs >> 1);
      boff[q][it] = (unsigned)(n0 + q * 128 + r) * K + (cs >> 1);
    }
  char* ldsA = lds;            // 2 bufs x (2 halves x 16KB)
  char* ldsB = lds + 65536;
  const int wdst = w * 1024;

#define STG_A(bufo, q, koff) do { \
    gload_lds16(A + aoff[q][0] + (koff), ldsA + (bufo) + (q) * 16384 + wdst); \
    gload_lds16(A + aoff[q][1] + (koff), ldsA + (bufo) + (q) * 16384 + 8192 + wdst); } while (0)
#define STG_B(bufo, q, koff) do { \
    gload_lds16(B + boff[q][0] + (koff), ldsB + (bufo) + (q) * 16384 + wdst); \
    gload_lds16(B + boff[q][1] + (koff), ldsB + (bufo) + (q) * 16384 + 8192 + wdst); } while (0)

  f32x4 acc[2][2][4][2] = {};   // [qi][qj][i][j]

  const int NT   = K >> 6;      // 16 K-tiles per m-tile
  const int NT2  = NT << 1;     // 32 across both m-tiles
  const int mAdv = K << 8;      // +256 rows, in elements

  // prologue: stage tile 0 -> buf 0, drain, sync
  STG_A(0, 0, 0); STG_B(0, 0, 0); STG_A(0, 1, 0); STG_B(0, 1, 0);
  asm volatile("s_waitcnt vmcnt(0)" ::: "memory");
  __builtin_amdgcn_s_barrier();

  int curo = 0;
  for (int t = 0; t < NT2; ++t) {
    const int nxto = curo ^ 32768;
    const bool st = (t + 1 < NT2);
    const int tn = t + 1;
    const int koffA = ((tn & (NT - 1)) << 6) + ((tn >= NT) ? mAdv : 0);
    const int koffB = (tn & (NT - 1)) << 6;
    const char* Ah = ldsA + curo + wm * 16384;
    const char* Bh = ldsB + curo + (wn >> 1) * 16384;

#define PHASE(QI, QJ, STAGE) do { \
    bf16x8 af0[4], af1[4], bv0[2], bv1[2]; \
    { const int cb0 = kg16 ^ swl; const int cb1 = (64 + kg16) ^ swl; \
      _Pragma("unroll") for (int i = 0; i < 4; ++i) { \
        af0[i] = *(const bf16x8*)(Ah + ((QI) * 64 + i * 16 + lr) * 128 + cb0); \
        af1[i] = *(const bf16x8*)(Ah + ((QI) * 64 + i * 16 + lr) * 128 + cb1); } \
      _Pragma("unroll") for (int j = 0; j < 2; ++j) { \
        bv0[j] = *(const bf16x8*)(Bh + (brow + (QJ) * 32 + j * 16 + lr) * 128 + cb0); \
        bv1[j] = *(const bf16x8*)(Bh + (brow + (QJ) * 32 + j * 16 + lr) * 128 + cb1); } } \
    if ((STAGE) == 1 && st) { STG_A(nxto, 0, koffA); STG_B(nxto, 0, koffB); } \
    if ((STAGE) == 2 && st) { STG_A(nxto, 1, koffA); STG_B(nxto, 1, koffB); } \
    __builtin_amdgcn_sched_barrier(0); \
    __builtin_amdgcn_s_barrier(); \
    asm volatile("s_waitcnt lgkmcnt(0)" ::: "memory"); \
    __builtin_amdgcn_s_setprio(1); \
    _Pragma("unroll") for (int i = 0; i < 4; ++i) { \
      acc[QI][QJ][i][0] = __builtin_amdgcn_mfma_f32_16x16x32_bf16(af0[i], bv0[0], acc[QI][QJ][i][0], 0, 0, 0); \
      acc[QI][QJ][i][1] = __builtin_amdgcn_mfma_f32_16x16x32_bf16(af0[i], bv0[1], acc[QI][QJ][i][1], 0, 0, 0); } \
    _Pragma("unroll") for (int i = 0; i < 4; ++i) { \
      acc[QI][QJ][i][0] = __builtin_amdgcn_mfma_f32_16x16x32_bf16(af1[i], bv1[0], acc[QI][QJ][i][0], 0, 0, 0); \
      acc[QI][QJ][i][1] = __builtin_amdgcn_mfma_f32_16x16x32_bf16(af1[i], bv1[1], acc[QI][QJ][i][1], 0, 0, 0); } \
    __builtin_amdgcn_s_setprio(0); \
  } while (0)

    PHASE(0, 0, 1);
    __builtin_amdgcn_s_barrier();
    PHASE(0, 1, 2);
    __builtin_amdgcn_s_barrier();
    PHASE(1, 0, 0);
    __builtin_amdgcn_s_barrier();
    PHASE(1, 1, 0);
    if (st) asm volatile("s_waitcnt vmcnt(0)" ::: "memory");
    __builtin_amdgcn_s_barrier();
#undef PHASE

    if (t == NT - 1) {
      write_c256(acc, C, bias, m0, n0, N, wm, wn, l);
      #pragma unroll
      for (int qi = 0; qi < 2; ++qi)
        #pragma unroll
        for (int qj = 0; qj < 2; ++qj)
          #pragma unroll
          for (int i = 0; i < 4; ++i)
            #pragma unroll
            for (int j = 0; j < 2; ++j)
              #pragma unroll
              for (int r = 0; r < 4; ++r)
                acc[qi][qj][i][j][r] = 0.f;
    }
    curo = nxto;
  }
  write_c256(acc, C, bias, m0 + 256, n0, N, wm, wn, l);
#undef STG_A
#undef STG_B
}

// ---------- launch ----------
extern "C" void kernel_launch(void* const* d_in, const int* in_sizes, int n_in,
                              void* d_out, int out_size, void* d_ws, size_t ws_size,
                              hipStream_t stream) {
  (void)in_sizes; (void)n_in; (void)out_size;
  const float* x    = (const float*)d_in[0];
  const float* P0   = (const float*)d_in[1];
  const float* P1   = (const float*)d_in[2];
  const float* P2   = (const float*)d_in[3];
  const float* P3   = (const float*)d_in[4];
  const float* K0   = (const float*)d_in[5];
  const float* K1   = (const float*)d_in[6];
  const float* K2   = (const float*)d_in[7];
  const float* bias = (const float*)d_in[8];

  unsigned short* S  = (unsigned short*)d_ws;
  unsigned short* T0 = S + (size_t)4 * (1u << 20);
  unsigned short* T1 = T0 + (1u << 20);
  unsigned short* Xb = T1 + (1u << 20);
  const size_t need = ((size_t)6 * (1u << 20) + (size_t)32768 * 1024) * 2;
  const bool have_xb = ws_size >= need;
  unsigned short* xbp = have_xb ? Xb : nullptr;

  // convert distributed in 8 slices of 512K ushort8-groups:
  // softmax gets 2 slices (1024 tail blocks), each of the 6 compose launches 1 slice (512 tail blocks)
  const int SL = 524288;
  const int smx_cvt = have_xb ? 2 * SL : 0;
  const int smx_grid = 4096 + (have_xb ? 1024 : 0);
  const int bd_grid  = 128 + (have_xb ? 512 : 0);
  const int g64_grid = 256 + (have_xb ? 512 : 0);
  const int g64_cvt  = have_xb ? SL : 0;

  softmax4_kernel<<<smx_grid, 256, 0, stream>>>(P0, P1, P2, P3, S, x, xbp, smx_cvt);

  const unsigned short* S0 = S;
  const unsigned short* S1 = S + (1u << 20);
  const unsigned short* S2 = S + (2u << 20);
  const unsigned short* S3 = S + (3u << 20);

  blockdiagT_kernel<<<bd_grid, 256, 0, stream>>>(K0, S0, T0, x, xbp, 2 * SL, g64_cvt);
  gemm_bt_kernel<64, false, false><<<g64_grid, 256, 0, stream>>>((const void*)S1, T0,
      (void*)T1, nullptr, 1024, 1024, 1024, 256, x, xbp, 3 * SL, g64_cvt);
  blockdiagT_kernel<<<bd_grid, 256, 0, stream>>>(K1, T1, T0, x, xbp, 4 * SL, g64_cvt);
  gemm_bt_kernel<64, false, false><<<g64_grid, 256, 0, stream>>>((const void*)S2, T0,
      (void*)T1, nullptr, 1024, 1024, 1024, 256, x, xbp, 5 * SL, g64_cvt);
  blockdiagT_kernel<<<bd_grid, 256, 0, stream>>>(K2, T1, T0, x, xbp, 6 * SL, g64_cvt);
  gemm_bt_kernel<64, false, false><<<g64_grid, 256, 0, stream>>>((const void*)S3, T0,
      (void*)T1, nullptr, 1024, 1024, 1024, 256, x, xbp, 7 * SL, g64_cvt);  // T1 = M [u][d]

  bool ok256 = false;
  if (have_xb) {
    hipError_t e = hipFuncSetAttribute((const void*)gemm256_kernel,
                                       hipFuncAttributeMaxDynamicSharedMemorySize, 131072);
    ok256 = (e == hipSuccess);
  }
  if (ok256) {
    gemm256_kernel<<<256, 512, 131072, stream>>>(Xb, T1, (float*)d_out, bias, 1024, 1024);
  } else if (have_xb) {
    gemm_bt_kernel<128, false, true><<<2048, 256, 0, stream>>>((const void*)Xb, T1,
        d_out, bias, 32768, 1024, 1024, 2048, nullptr, nullptr, 0, 0);
  } else {
    gemm_bt_kernel<128, true, true><<<2048, 256, 0, stream>>>((const void*)x, T1,
        d_out, bias, 32768, 1024, 1024, 2048, nullptr, nullptr, 0, 0);
  }
}

// Round 6
// 190.966 us; speedup vs baseline: 1.4550x; 1.4550x over previous
//
#include <hip/hip_runtime.h>
#include <hip/hip_bf16.h>

// ---------- helpers ----------
typedef __bf16 bf16x8 __attribute__((ext_vector_type(8)));
typedef float f32x4 __attribute__((ext_vector_type(4)));
typedef unsigned short u16x8 __attribute__((ext_vector_type(8)));

__device__ __forceinline__ unsigned short f2bf(float f) {
  unsigned u = __float_as_uint(f);
  u += 0x7FFF + ((u >> 16) & 1);          // RNE
  return (unsigned short)(u >> 16);
}
__device__ __forceinline__ float bf2f(unsigned short h) {
  return __uint_as_float((unsigned)h << 16);
}

__device__ __forceinline__ void gload_lds16(const void* g, void* l) {
  __builtin_amdgcn_global_load_lds(
      (const __attribute__((address_space(1))) void*)g,
      (__attribute__((address_space(3))) void*)l, 16, 0, 0);
}

#define LBAR() do { asm volatile("s_waitcnt lgkmcnt(0)" ::: "memory"); \
                    __builtin_amdgcn_s_barrier(); } while (0)

// grid-strided fp32->bf16 convert slice, run by tail blocks of latency-bound launches
__device__ __forceinline__ void convert_slice(const float* __restrict__ x,
                                              unsigned short* __restrict__ xb,
                                              int base8, int cnt8, int cb, int nb)
{
  int i = cb * 256 + (int)threadIdx.x;
  const int stride = nb * 256;
  for (; i < cnt8; i += stride) {
    const size_t g = (size_t)(base8 + i);
    float4 v0 = ((const float4*)x)[2 * g];
    float4 v1 = ((const float4*)x)[2 * g + 1];
    u16x8 uv;
    uv[0] = f2bf(v0.x); uv[1] = f2bf(v0.y); uv[2] = f2bf(v0.z); uv[3] = f2bf(v0.w);
    uv[4] = f2bf(v1.x); uv[5] = f2bf(v1.y); uv[6] = f2bf(v1.z); uv[7] = f2bf(v1.w);
    ((u16x8*)xb)[g] = uv;
  }
}

// ---------- 1) row softmax of 4 P matrices -> bf16 (+ convert tail blocks) ----------
__global__ __launch_bounds__(256)
void softmax4_kernel(const float* __restrict__ P0, const float* __restrict__ P1,
                     const float* __restrict__ P2, const float* __restrict__ P3,
                     unsigned short* __restrict__ S,
                     const float* __restrict__ cvx, unsigned short* __restrict__ cvxb,
                     int cvt_cnt)
{
  if (blockIdx.x >= 4096) {
    convert_slice(cvx, cvxb, 0, cvt_cnt, blockIdx.x - 4096, gridDim.x - 4096);
    return;
  }
  const int bid = blockIdx.x;
  const int mat = bid >> 10, row = bid & 1023;
  const float* P = (mat == 0 ? P0 : mat == 1 ? P1 : mat == 2 ? P2 : P3) + (size_t)row * 1024;
  unsigned short* out = S + ((size_t)mat << 20) + (size_t)row * 1024;
  const int t = threadIdx.x, w = t >> 6, l = t & 63;
  float4 v = ((const float4*)P)[t];
  float mx = fmaxf(fmaxf(v.x, v.y), fmaxf(v.z, v.w));
  #pragma unroll
  for (int off = 32; off > 0; off >>= 1) mx = fmaxf(mx, __shfl_xor(mx, off));
  __shared__ float redA[4], redB[4];
  if (l == 0) redA[w] = mx;
  __syncthreads();
  mx = fmaxf(fmaxf(redA[0], redA[1]), fmaxf(redA[2], redA[3]));
  float e0 = __expf(v.x - mx), e1 = __expf(v.y - mx);
  float e2 = __expf(v.z - mx), e3 = __expf(v.w - mx);
  float s = e0 + e1 + e2 + e3;
  #pragma unroll
  for (int off = 32; off > 0; off >>= 1) s += __shfl_xor(s, off);
  if (l == 0) redB[w] = s;
  __syncthreads();
  s = redB[0] + redB[1] + redB[2] + redB[3];
  float inv = 1.0f / s;
  ushort4 o;
  o.x = f2bf(e0 * inv); o.y = f2bf(e1 * inv);
  o.z = f2bf(e2 * inv); o.w = f2bf(e3 * inv);
  ((ushort4*)out)[t] = o;
}

// ---------- 2) out^T = (blockdiag(K)^T @ in)^T  (+ convert tail blocks) ----------
__global__ __launch_bounds__(256)
void blockdiagT_kernel(const float* __restrict__ Kb, const unsigned short* __restrict__ in,
                       unsigned short* __restrict__ outT,
                       const float* __restrict__ cvx, unsigned short* __restrict__ cvxb,
                       int cvt_base, int cvt_cnt)
{
  if (blockIdx.x >= 128) {
    convert_slice(cvx, cvxb, cvt_base, cvt_cnt, blockIdx.x - 128, gridDim.x - 128);
    return;
  }
  const int n = blockIdx.x >> 2;
  const int c = (blockIdx.x & 3) * 256 + threadIdx.x;
  __shared__ float Ks[32][33];
  for (int t = threadIdx.x; t < 1024; t += 256)
    Ks[t >> 5][t & 31] = Kb[n * 1024 + t];
  __syncthreads();
  float ri[32];
  #pragma unroll
  for (int i = 0; i < 32; ++i)
    ri[i] = bf2f(in[(size_t)(n * 32 + i) * 1024 + c]);
  unsigned short ov[32];
  #pragma unroll
  for (int o = 0; o < 32; ++o) {
    float acc = 0.f;
    #pragma unroll
    for (int i = 0; i < 32; ++i) acc = fmaf(Ks[i][o], ri[i], acc);
    ov[o] = f2bf(acc);
  }
  u16x8* dst = (u16x8*)(outT + (size_t)c * 1024 + n * 32);
  const u16x8* src = (const u16x8*)ov;
  #pragma unroll
  for (int q = 0; q < 4; ++q) dst[q] = src[q];
}

// ---------- 3a) 2-barrier GEMM (compose chain + fallback): C = A @ B^T ----------
template<int TILE, bool A_FP32, bool OUT_BIAS>
__global__ __launch_bounds__(256)
void gemm_bt_kernel(const void* __restrict__ Av, const unsigned short* __restrict__ B,
                    void* __restrict__ Cv, const float* __restrict__ bias,
                    int M, int N, int K, int nprim,
                    const float* cvx, unsigned short* cvxb, int cvt_base, int cvt_cnt)
{
  if ((int)blockIdx.x >= nprim) {
    convert_slice(cvx, cvxb, cvt_base, cvt_cnt, blockIdx.x - nprim, gridDim.x - nprim);
    return;
  }
  constexpr int FR  = TILE / 32;
  constexpr int SIT = TILE / 32;
  __shared__ unsigned short Asm[TILE * 64];
  __shared__ unsigned short Bsm[TILE * 64];
  const int tid = threadIdx.x;
  const int w = tid >> 6, l = tid & 63;
  const int bid = blockIdx.x;
  const int cpx = nprim >> 3;
  const int swz = (bid & 7) * cpx + (bid >> 3);
  const int ntn = N / TILE;
  const int n0 = (swz % ntn) * TILE;
  const int m0 = (swz / ntn) * TILE;
  const int wr = (w >> 1) * (TILE / 2), wc = (w & 1) * (TILE / 2);
  const int lr = l & 15, kg = (l >> 4) << 3;

  f32x4 acc[FR][FR] = {};
  const int KT = K >> 6;
  for (int kt = 0; kt < KT; ++kt) {
    const int k0 = kt << 6;
    if (kt) __syncthreads();
    #pragma unroll
    for (int it = 0; it < SIT; ++it) {
      int li = it * 256 + tid;
      int row = li >> 3, c8 = (li & 7) << 3;
      const unsigned short* g = B + (size_t)(n0 + row) * K + (k0 + c8);
      gload_lds16(g, (char*)Bsm + it * 4096 + w * 1024);
    }
    if (A_FP32) {
      const float* Af = (const float*)Av;
      #pragma unroll
      for (int p = 0; p < SIT; ++p) {
        int row = (tid >> 3) + p * 32;
        int c8 = (tid & 7) << 3;
        const float* g = Af + (size_t)(m0 + row) * K + (k0 + c8);
        float4 v0 = ((const float4*)g)[0];
        float4 v1 = ((const float4*)g)[1];
        u16x8 uv;
        uv[0] = f2bf(v0.x); uv[1] = f2bf(v0.y); uv[2] = f2bf(v0.z); uv[3] = f2bf(v0.w);
        uv[4] = f2bf(v1.x); uv[5] = f2bf(v1.y); uv[6] = f2bf(v1.z); uv[7] = f2bf(v1.w);
        *(u16x8*)&Asm[row * 64 + c8] = uv;
      }
    } else {
      const unsigned short* Ab = (const unsigned short*)Av;
      #pragma unroll
      for (int it = 0; it < SIT; ++it) {
        int li = it * 256 + tid;
        int row = li >> 3, c8 = (li & 7) << 3;
        const unsigned short* g = Ab + (size_t)(m0 + row) * K + (k0 + c8);
        gload_lds16(g, (char*)Asm + it * 4096 + w * 1024);
      }
    }
    __syncthreads();
    #pragma unroll
    for (int ks = 0; ks < 2; ++ks) {
      const int kb = ks * 32 + kg;
      bf16x8 af[FR], bfr[FR];
      #pragma unroll
      for (int i = 0; i < FR; ++i)
        af[i] = *(const bf16x8*)&Asm[(wr + i * 16 + lr) * 64 + kb];
      #pragma unroll
      for (int j = 0; j < FR; ++j)
        bfr[j] = *(const bf16x8*)&Bsm[(wc + j * 16 + lr) * 64 + kb];
      #pragma unroll
      for (int i = 0; i < FR; ++i)
        #pragma unroll
        for (int j = 0; j < FR; ++j)
          acc[i][j] = __builtin_amdgcn_mfma_f32_16x16x32_bf16(af[i], bfr[j], acc[i][j], 0, 0, 0);
    }
  }
  const int cr = (l >> 4) << 2;
  const int cc = l & 15;
  if (OUT_BIAS) {
    float* C = (float*)Cv;
    #pragma unroll
    for (int j = 0; j < FR; ++j) {
      int col = n0 + wc + j * 16 + cc;
      float bv = bias[col];
      #pragma unroll
      for (int i = 0; i < FR; ++i) {
        int rbase = m0 + wr + i * 16 + cr;
        #pragma unroll
        for (int r = 0; r < 4; ++r)
          C[(size_t)(rbase + r) * N + col] = acc[i][j][r] + bv;
      }
    }
  } else {
    unsigned short* C = (unsigned short*)Cv;
    #pragma unroll
    for (int j = 0; j < FR; ++j) {
      int col = n0 + wc + j * 16 + cc;
      #pragma unroll
      for (int i = 0; i < FR; ++i) {
        int rbase = m0 + wr + i * 16 + cr;
        #pragma unroll
        for (int r = 0; r < 4; ++r)
          C[(size_t)(rbase + r) * N + col] = f2bf(acc[i][j][r]);
      }
    }
  }
}

// ---------- 3b) 256x256 8-phase GEMM (final): C = A @ B^T + bias, fp32 out ----------
// ROUND-3 VERBATIM (best measured: 87.5 us, MfmaUtil 32%, 0 bank conflicts).
// 8 waves (wm=w>>2, wn=w&3). Per-wave C: quadrants (qi,qj): rows qi*128+wm*64+[0,64),
// cols qj*128+wn*32+[0,32). Phase p=(qi,qj) consumes exactly A-half qi, B-half qj.
// Stage order per tile: A0,B0,B1,A1 -> counted vmcnt(6) steady state, 4/2/0 drain.
// Per-wave vmcnt + per-phase barrier = cross-wave publish of each staged half.
template<int QI, int QJ>
__device__ __forceinline__ void phase_compute(const char* Ab, const char* Bb,
    int wm, int wn, int lr, int klo, int sw, f32x4 (&accq)[4][2])
{
  const char* Ah = Ab + QI * 16384;
  const char* Bh = Bb + QJ * 16384;
  #pragma unroll
  for (int ks = 0; ks < 2; ++ks) {
    const int cb = (ks * 64 + klo) ^ sw;
    bf16x8 av[4], bv[2];
    #pragma unroll
    for (int i = 0; i < 4; ++i) {
      const int ra = wm * 64 + i * 16 + lr;
      av[i] = *(const bf16x8*)(Ah + ra * 128 + cb);
    }
    #pragma unroll
    for (int j = 0; j < 2; ++j) {
      const int rb = wn * 32 + j * 16 + lr;
      bv[j] = *(const bf16x8*)(Bh + rb * 128 + cb);
    }
    __builtin_amdgcn_s_setprio(1);
    #pragma unroll
    for (int i = 0; i < 4; ++i)
      #pragma unroll
      for (int j = 0; j < 2; ++j)
        accq[i][j] = __builtin_amdgcn_mfma_f32_16x16x32_bf16(av[i], bv[j], accq[i][j], 0, 0, 0);
    __builtin_amdgcn_s_setprio(0);
  }
}

__global__ __launch_bounds__(512, 2)
void gemm256_kernel(const unsigned short* __restrict__ A,   // [M,K] bf16
                    const unsigned short* __restrict__ B,   // [N,K] bf16
                    float* __restrict__ C, const float* __restrict__ bias,
                    int N, int K)
{
  extern __shared__ __align__(16) char lds[];   // 131072 B
  const int tid = threadIdx.x;
  const int w = tid >> 6, l = tid & 63;
  const int wm = w >> 2, wn = w & 3;
  const int lr = l & 15;
  const int klo = (l >> 4) << 4;      // byte col of k-slot
  const int sw  = (lr & 7) << 4;      // read-side XOR swizzle

  const int nwg = gridDim.x;
  const int bid = blockIdx.x;
  const int cpx = nwg >> 3;
  const int swz = (bid & 7) * cpx + (bid >> 3);
  const int ntn = N >> 8;
  const int n0 = (swz % ntn) << 8;
  const int m0 = (swz / ntn) << 8;

  // staging source offsets (elements), inverse-swizzled global col
  unsigned int aoff[2][2], boff[2][2];
  #pragma unroll
  for (int q = 0; q < 2; ++q)
    #pragma unroll
    for (int it = 0; it < 2; ++it) {
      int L = it * 8192 + tid * 16;           // byte pos within half-tile
      int r = L >> 7;                          // row 0..127
      int cs = (L & 127) ^ ((r & 7) << 4);     // source col bytes (pre-swizzled)
      aoff[q][it] = (unsigned)(m0 + q * 128 + r) * K + (cs >> 1);
      boff[q][it] = (unsigned)(n0 + q * 128 + r) * K + (cs >> 1);
    }
  char* ldsA = lds;
  char* ldsB = lds + 65536;
  const int wdst = w * 1024;

#define STG_A(bufo, q, k0) do { \
    gload_lds16(A + aoff[q][0] + (k0), ldsA + (bufo) + (q) * 16384 + wdst); \
    gload_lds16(A + aoff[q][1] + (k0), ldsA + (bufo) + (q) * 16384 + 8192 + wdst); } while (0)
#define STG_B(bufo, q, k0) do { \
    gload_lds16(B + boff[q][0] + (k0), ldsB + (bufo) + (q) * 16384 + wdst); \
    gload_lds16(B + boff[q][1] + (k0), ldsB + (bufo) + (q) * 16384 + 8192 + wdst); } while (0)

  f32x4 acc[2][2][4][2] = {};

  // prologue: stage tile 0 into buf 0 (order A0,B0,B1,A1)
  STG_A(0, 0, 0); STG_B(0, 0, 0); STG_B(0, 1, 0); STG_A(0, 1, 0);

  const int NT = K >> 6;
  int curo = 0;
  for (int t = 0; t < NT - 1; ++t) {
    const int nxto = curo ^ 32768;
    const int k1 = (t + 1) << 6;
    // phase 0: quadrant (0,0); stage next A0; drain cur A0,B0
    STG_A(nxto, 0, k1);
    asm volatile("s_waitcnt vmcnt(6)" ::: "memory");
    LBAR();
    phase_compute<0, 0>(ldsA + curo, ldsB + curo, wm, wn, lr, klo, sw, acc[0][0]);
    // phase 1: quadrant (0,1); stage next B0; drain cur B1
    STG_B(nxto, 0, k1);
    asm volatile("s_waitcnt vmcnt(6)" ::: "memory");
    LBAR();
    phase_compute<0, 1>(ldsA + curo, ldsB + curo, wm, wn, lr, klo, sw, acc[0][1]);
    // phase 2: quadrant (1,0); stage next B1; drain cur A1
    STG_B(nxto, 1, k1);
    asm volatile("s_waitcnt vmcnt(6)" ::: "memory");
    LBAR();
    phase_compute<1, 0>(ldsA + curo, ldsB + curo, wm, wn, lr, klo, sw, acc[1][0]);
    // phase 3: quadrant (1,1); stage next A1; nothing new needed
    STG_A(nxto, 1, k1);
    phase_compute<1, 1>(ldsA + curo, ldsB + curo, wm, wn, lr, klo, sw, acc[1][1]);
    curo = nxto;
  }
  // last tile: no staging, drain 4 -> 2 -> 0
  asm volatile("s_waitcnt vmcnt(4)" ::: "memory");
  LBAR();
  phase_compute<0, 0>(ldsA + curo, ldsB + curo, wm, wn, lr, klo, sw, acc[0][0]);
  asm volatile("s_waitcnt vmcnt(2)" ::: "memory");
  LBAR();
  phase_compute<0, 1>(ldsA + curo, ldsB + curo, wm, wn, lr, klo, sw, acc[0][1]);
  asm volatile("s_waitcnt vmcnt(0)" ::: "memory");
  LBAR();
  phase_compute<1, 0>(ldsA + curo, ldsB + curo, wm, wn, lr, klo, sw, acc[1][0]);
  phase_compute<1, 1>(ldsA + curo, ldsB + curo, wm, wn, lr, klo, sw, acc[1][1]);

  // epilogue: C/D layout col = lane&15, row = (lane>>4)*4 + reg
  const int cr = (l >> 4) << 2;
  const int cc = l & 15;
  #pragma unroll
  for (int qi = 0; qi < 2; ++qi)
    #pragma unroll
    for (int qj = 0; qj < 2; ++qj)
      #pragma unroll
      for (int j = 0; j < 2; ++j) {
        const int col = n0 + qj * 128 + wn * 32 + j * 16 + cc;
        const float bv = bias[col];
        #pragma unroll
        for (int i = 0; i < 4; ++i) {
          const int rbase = m0 + qi * 128 + wm * 64 + i * 16 + cr;
          #pragma unroll
          for (int r = 0; r < 4; ++r)
            C[(size_t)(rbase + r) * N + col] = acc[qi][qj][i][j][r] + bv;
        }
      }
#undef STG_A
#undef STG_B
}

// ---------- launch ----------
extern "C" void kernel_launch(void* const* d_in, const int* in_sizes, int n_in,
                              void* d_out, int out_size, void* d_ws, size_t ws_size,
                              hipStream_t stream) {
  (void)in_sizes; (void)n_in; (void)out_size;
  const float* x    = (const float*)d_in[0];
  const float* P0   = (const float*)d_in[1];
  const float* P1   = (const float*)d_in[2];
  const float* P2   = (const float*)d_in[3];
  const float* P3   = (const float*)d_in[4];
  const float* K0   = (const float*)d_in[5];
  const float* K1   = (const float*)d_in[6];
  const float* K2   = (const float*)d_in[7];
  const float* bias = (const float*)d_in[8];

  unsigned short* S  = (unsigned short*)d_ws;
  unsigned short* T0 = S + (size_t)4 * (1u << 20);
  unsigned short* T1 = T0 + (1u << 20);
  unsigned short* Xb = T1 + (1u << 20);
  const size_t need = ((size_t)6 * (1u << 20) + (size_t)32768 * 1024) * 2;
  const bool have_xb = ws_size >= need;
  unsigned short* xbp = have_xb ? Xb : nullptr;

  // convert distributed in 8 slices of 512K ushort8-groups:
  // softmax gets 2 slices (1024 tail blocks), each of the 6 compose launches 1 slice
  const int SL = 524288;
  const int smx_cvt = have_xb ? 2 * SL : 0;
  const int smx_grid = 4096 + (have_xb ? 1024 : 0);
  const int bd_grid  = 128 + (have_xb ? 512 : 0);
  const int g64_grid = 256 + (have_xb ? 512 : 0);
  const int g64_cvt  = have_xb ? SL : 0;

  softmax4_kernel<<<smx_grid, 256, 0, stream>>>(P0, P1, P2, P3, S, x, xbp, smx_cvt);

  const unsigned short* S0 = S;
  const unsigned short* S1 = S + (1u << 20);
  const unsigned short* S2 = S + (2u << 20);
  const unsigned short* S3 = S + (3u << 20);

  blockdiagT_kernel<<<bd_grid, 256, 0, stream>>>(K0, S0, T0, x, xbp, 2 * SL, g64_cvt);
  gemm_bt_kernel<64, false, false><<<g64_grid, 256, 0, stream>>>((const void*)S1, T0,
      (void*)T1, nullptr, 1024, 1024, 1024, 256, x, xbp, 3 * SL, g64_cvt);
  blockdiagT_kernel<<<bd_grid, 256, 0, stream>>>(K1, T1, T0, x, xbp, 4 * SL, g64_cvt);
  gemm_bt_kernel<64, false, false><<<g64_grid, 256, 0, stream>>>((const void*)S2, T0,
      (void*)T1, nullptr, 1024, 1024, 1024, 256, x, xbp, 5 * SL, g64_cvt);
  blockdiagT_kernel<<<bd_grid, 256, 0, stream>>>(K2, T1, T0, x, xbp, 6 * SL, g64_cvt);
  gemm_bt_kernel<64, false, false><<<g64_grid, 256, 0, stream>>>((const void*)S3, T0,
      (void*)T1, nullptr, 1024, 1024, 1024, 256, x, xbp, 7 * SL, g64_cvt);  // T1 = M [u][d]

  bool ok256 = false;
  if (have_xb) {
    hipError_t e = hipFuncSetAttribute((const void*)gemm256_kernel,
                                       hipFuncAttributeMaxDynamicSharedMemorySize, 131072);
    ok256 = (e == hipSuccess);
  }
  if (ok256) {
    gemm256_kernel<<<512, 512, 131072, stream>>>(Xb, T1, (float*)d_out, bias, 1024, 1024);
  } else if (have_xb) {
    gemm_bt_kernel<128, false, true><<<2048, 256, 0, stream>>>((const void*)Xb, T1,
        d_out, bias, 32768, 1024, 1024, 2048, nullptr, nullptr, 0, 0);
  } else {
    gemm_bt_kernel<128, true, true><<<2048, 256, 0, stream>>>((const void*)x, T1,
        d_out, bias, 32768, 1024, 1024, 2048, nullptr, nullptr, 0, 0);
  }
}

// Round 7
// 161.184 us; speedup vs baseline: 1.7239x; 1.1848x over previous
//
#include <hip/hip_runtime.h>
#include <hip/hip_bf16.h>

// ---------- helpers ----------
typedef __bf16 bf16x8 __attribute__((ext_vector_type(8)));
typedef float f32x4 __attribute__((ext_vector_type(4)));
typedef unsigned short u16x8 __attribute__((ext_vector_type(8)));

__device__ __forceinline__ unsigned short f2bf(float f) {
  unsigned u = __float_as_uint(f);
  u += 0x7FFF + ((u >> 16) & 1);          // RNE
  return (unsigned short)(u >> 16);
}
__device__ __forceinline__ float bf2f(unsigned short h) {
  return __uint_as_float((unsigned)h << 16);
}

__device__ __forceinline__ void gload_lds16(const void* g, void* l) {
  __builtin_amdgcn_global_load_lds(
      (const __attribute__((address_space(1))) void*)g,
      (__attribute__((address_space(3))) void*)l, 16, 0, 0);
}

#define LBAR() do { asm volatile("s_waitcnt lgkmcnt(0)" ::: "memory"); \
                    __builtin_amdgcn_s_barrier(); } while (0)

// grid-strided fp32->bf16 convert slice, run by tail blocks of latency-bound launches
__device__ __forceinline__ void convert_slice(const float* __restrict__ x,
                                              unsigned short* __restrict__ xb,
                                              int base8, int cnt8, int cb, int nb)
{
  int i = cb * 256 + (int)threadIdx.x;
  const int stride = nb * 256;
  for (; i < cnt8; i += stride) {
    const size_t g = (size_t)(base8 + i);
    float4 v0 = ((const float4*)x)[2 * g];
    float4 v1 = ((const float4*)x)[2 * g + 1];
    u16x8 uv;
    uv[0] = f2bf(v0.x); uv[1] = f2bf(v0.y); uv[2] = f2bf(v0.z); uv[3] = f2bf(v0.w);
    uv[4] = f2bf(v1.x); uv[5] = f2bf(v1.y); uv[6] = f2bf(v1.z); uv[7] = f2bf(v1.w);
    ((u16x8*)xb)[g] = uv;
  }
}

// ---------- 1) row softmax of 4 P matrices -> bf16 (+ convert tail blocks) ----------
__global__ __launch_bounds__(256)
void softmax4_kernel(const float* __restrict__ P0, const float* __restrict__ P1,
                     const float* __restrict__ P2, const float* __restrict__ P3,
                     unsigned short* __restrict__ S,
                     const float* __restrict__ cvx, unsigned short* __restrict__ cvxb,
                     int cvt_cnt)
{
  if (blockIdx.x >= 4096) {
    convert_slice(cvx, cvxb, 0, cvt_cnt, blockIdx.x - 4096, gridDim.x - 4096);
    return;
  }
  const int bid = blockIdx.x;
  const int mat = bid >> 10, row = bid & 1023;
  const float* P = (mat == 0 ? P0 : mat == 1 ? P1 : mat == 2 ? P2 : P3) + (size_t)row * 1024;
  unsigned short* out = S + ((size_t)mat << 20) + (size_t)row * 1024;
  const int t = threadIdx.x, w = t >> 6, l = t & 63;
  float4 v = ((const float4*)P)[t];
  float mx = fmaxf(fmaxf(v.x, v.y), fmaxf(v.z, v.w));
  #pragma unroll
  for (int off = 32; off > 0; off >>= 1) mx = fmaxf(mx, __shfl_xor(mx, off));
  __shared__ float redA[4], redB[4];
  if (l == 0) redA[w] = mx;
  __syncthreads();
  mx = fmaxf(fmaxf(redA[0], redA[1]), fmaxf(redA[2], redA[3]));
  float e0 = __expf(v.x - mx), e1 = __expf(v.y - mx);
  float e2 = __expf(v.z - mx), e3 = __expf(v.w - mx);
  float s = e0 + e1 + e2 + e3;
  #pragma unroll
  for (int off = 32; off > 0; off >>= 1) s += __shfl_xor(s, off);
  if (l == 0) redB[w] = s;
  __syncthreads();
  s = redB[0] + redB[1] + redB[2] + redB[3];
  float inv = 1.0f / s;
  ushort4 o;
  o.x = f2bf(e0 * inv); o.y = f2bf(e1 * inv);
  o.z = f2bf(e2 * inv); o.w = f2bf(e3 * inv);
  ((ushort4*)out)[t] = o;
}

// ---------- 2) blockdiagT body: outT = ((blockdiag(K))^T @ in)^T ----------
__device__ __forceinline__ void bdT_body(const float* __restrict__ Kb,
                                         const unsigned short* __restrict__ in,
                                         unsigned short* __restrict__ outT, int bid)
{
  const int n = bid >> 2;
  const int c = (bid & 3) * 256 + threadIdx.x;
  __shared__ float Ks[32][33];
  for (int t = threadIdx.x; t < 1024; t += 256)
    Ks[t >> 5][t & 31] = Kb[n * 1024 + t];
  __syncthreads();
  float ri[32];
  #pragma unroll
  for (int i = 0; i < 32; ++i)
    ri[i] = bf2f(in[(size_t)(n * 32 + i) * 1024 + c]);
  unsigned short ov[32];
  #pragma unroll
  for (int o = 0; o < 32; ++o) {
    float acc = 0.f;
    #pragma unroll
    for (int i = 0; i < 32; ++i) acc = fmaf(Ks[i][o], ri[i], acc);
    ov[o] = f2bf(acc);
  }
  u16x8* dst = (u16x8*)(outT + (size_t)c * 1024 + n * 32);
  const u16x8* src = (const u16x8*)ov;
  #pragma unroll
  for (int q = 0; q < 4; ++q) dst[q] = src[q];
}

// dual: blocks 0-127 -> (Ka,ina,outa), 128-255 -> (Kb2,inb,outb), >=256 convert
__global__ __launch_bounds__(256)
void blockdiagT_dual_kernel(const float* Ka, const unsigned short* ina, unsigned short* outa,
                            const float* Kb2, const unsigned short* inb, unsigned short* outb,
                            const float* cvx, unsigned short* cvxb, int cvt_base, int cvt_cnt)
{
  const int bid = blockIdx.x;
  if (bid >= 256) {
    convert_slice(cvx, cvxb, cvt_base, cvt_cnt, bid - 256, gridDim.x - 256);
    return;
  }
  const bool sec = bid >= 128;
  bdT_body(sec ? Kb2 : Ka, sec ? inb : ina, sec ? outb : outa, sec ? bid - 128 : bid);
}

// ---------- 2b) right-blockdiag: Zt[c, n*32+i] = sum_o Yt[c, n*32+o] * K[n][o][i] ----------
__global__ __launch_bounds__(256)
void bdiag_right_kernel(const float* __restrict__ Kb, const unsigned short* __restrict__ Yt,
                        unsigned short* __restrict__ Zt,
                        const float* cvx, unsigned short* cvxb, int cvt_base, int cvt_cnt)
{
  const int bid = blockIdx.x;
  if (bid >= 256) {
    convert_slice(cvx, cvxb, cvt_base, cvt_cnt, bid - 256, gridDim.x - 256);
    return;
  }
  const int n = bid & 31, rowg = bid >> 5;
  __shared__ float Ks[32][32];   // Ks[o][i]
  for (int t = threadIdx.x; t < 1024; t += 256)
    Ks[t >> 5][t & 31] = Kb[n * 1024 + t];
  __syncthreads();
  const int row = rowg * 128 + ((int)threadIdx.x >> 1);
  const int ih = ((int)threadIdx.x & 1) * 16;
  const unsigned short* yrow = Yt + (size_t)row * 1024 + n * 32;
  float y[32];
  #pragma unroll
  for (int q = 0; q < 4; ++q) {
    u16x8 v = ((const u16x8*)yrow)[q];
    #pragma unroll
    for (int e = 0; e < 8; ++e) y[q * 8 + e] = bf2f(v[e]);
  }
  float acc[16] = {};
  #pragma unroll
  for (int o = 0; o < 32; ++o)
    #pragma unroll
    for (int ii = 0; ii < 16; ++ii)
      acc[ii] = fmaf(y[o], Ks[o][ih + ii], acc[ii]);
  u16x8 ov[2];
  #pragma unroll
  for (int ii = 0; ii < 16; ++ii) ov[ii >> 3][ii & 7] = f2bf(acc[ii]);
  u16x8* dst = (u16x8*)(Zt + (size_t)row * 1024 + n * 32 + ih);
  dst[0] = ov[0]; dst[1] = ov[1];
}

// ---------- 3a) 2-barrier GEMM body (compose chain + fallback): C = A @ B^T ----------
template<int TILE, bool A_FP32, bool OUT_BIAS>
__device__ __forceinline__ void gemm_body(const void* __restrict__ Av,
                                          const unsigned short* __restrict__ B,
                                          void* __restrict__ Cv, const float* __restrict__ bias,
                                          int N, int K, int nprim, int bid)
{
  constexpr int FR  = TILE / 32;
  constexpr int SIT = TILE / 32;
  __shared__ unsigned short Asm[TILE * 64];
  __shared__ unsigned short Bsm[TILE * 64];
  const int tid = threadIdx.x;
  const int w = tid >> 6, l = tid & 63;
  const int cpx = nprim >> 3;
  const int swz = (bid & 7) * cpx + (bid >> 3);
  const int ntn = N / TILE;
  const int n0 = (swz % ntn) * TILE;
  const int m0 = (swz / ntn) * TILE;
  const int wr = (w >> 1) * (TILE / 2), wc = (w & 1) * (TILE / 2);
  const int lr = l & 15, kg = (l >> 4) << 3;

  f32x4 acc[FR][FR] = {};
  const int KT = K >> 6;
  for (int kt = 0; kt < KT; ++kt) {
    const int k0 = kt << 6;
    if (kt) __syncthreads();
    #pragma unroll
    for (int it = 0; it < SIT; ++it) {
      int li = it * 256 + tid;
      int row = li >> 3, c8 = (li & 7) << 3;
      const unsigned short* g = B + (size_t)(n0 + row) * K + (k0 + c8);
      gload_lds16(g, (char*)Bsm + it * 4096 + w * 1024);
    }
    if (A_FP32) {
      const float* Af = (const float*)Av;
      #pragma unroll
      for (int p = 0; p < SIT; ++p) {
        int row = (tid >> 3) + p * 32;
        int c8 = (tid & 7) << 3;
        const float* g = Af + (size_t)(m0 + row) * K + (k0 + c8);
        float4 v0 = ((const float4*)g)[0];
        float4 v1 = ((const float4*)g)[1];
        u16x8 uv;
        uv[0] = f2bf(v0.x); uv[1] = f2bf(v0.y); uv[2] = f2bf(v0.z); uv[3] = f2bf(v0.w);
        uv[4] = f2bf(v1.x); uv[5] = f2bf(v1.y); uv[6] = f2bf(v1.z); uv[7] = f2bf(v1.w);
        *(u16x8*)&Asm[row * 64 + c8] = uv;
      }
    } else {
      const unsigned short* Ab = (const unsigned short*)Av;
      #pragma unroll
      for (int it = 0; it < SIT; ++it) {
        int li = it * 256 + tid;
        int row = li >> 3, c8 = (li & 7) << 3;
        const unsigned short* g = Ab + (size_t)(m0 + row) * K + (k0 + c8);
        gload_lds16(g, (char*)Asm + it * 4096 + w * 1024);
      }
    }
    __syncthreads();
    #pragma unroll
    for (int ks = 0; ks < 2; ++ks) {
      const int kb = ks * 32 + kg;
      bf16x8 af[FR], bfr[FR];
      #pragma unroll
      for (int i = 0; i < FR; ++i)
        af[i] = *(const bf16x8*)&Asm[(wr + i * 16 + lr) * 64 + kb];
      #pragma unroll
      for (int j = 0; j < FR; ++j)
        bfr[j] = *(const bf16x8*)&Bsm[(wc + j * 16 + lr) * 64 + kb];
      #pragma unroll
      for (int i = 0; i < FR; ++i)
        #pragma unroll
        for (int j = 0; j < FR; ++j)
          acc[i][j] = __builtin_amdgcn_mfma_f32_16x16x32_bf16(af[i], bfr[j], acc[i][j], 0, 0, 0);
    }
  }
  const int cr = (l >> 4) << 2;
  const int cc = l & 15;
  if (OUT_BIAS) {
    float* C = (float*)Cv;
    #pragma unroll
    for (int j = 0; j < FR; ++j) {
      int col = n0 + wc + j * 16 + cc;
      float bv = bias[col];
      #pragma unroll
      for (int i = 0; i < FR; ++i) {
        int rbase = m0 + wr + i * 16 + cr;
        #pragma unroll
        for (int r = 0; r < 4; ++r)
          C[(size_t)(rbase + r) * N + col] = acc[i][j][r] + bv;
      }
    }
  } else {
    unsigned short* C = (unsigned short*)Cv;
    #pragma unroll
    for (int j = 0; j < FR; ++j) {
      int col = n0 + wc + j * 16 + cc;
      #pragma unroll
      for (int i = 0; i < FR; ++i) {
        int rbase = m0 + wr + i * 16 + cr;
        #pragma unroll
        for (int r = 0; r < 4; ++r)
          C[(size_t)(rbase + r) * N + col] = f2bf(acc[i][j][r]);
      }
    }
  }
}

template<int TILE, bool A_FP32, bool OUT_BIAS>
__global__ __launch_bounds__(256)
void gemm_bt_kernel(const void* __restrict__ Av, const unsigned short* __restrict__ B,
                    void* __restrict__ Cv, const float* __restrict__ bias,
                    int N, int K, int nprim,
                    const float* cvx, unsigned short* cvxb, int cvt_base, int cvt_cnt)
{
  if ((int)blockIdx.x >= nprim) {
    convert_slice(cvx, cvxb, cvt_base, cvt_cnt, blockIdx.x - nprim, gridDim.x - nprim);
    return;
  }
  gemm_body<TILE, A_FP32, OUT_BIAS>(Av, B, Cv, bias, N, K, nprim, blockIdx.x);
}

// dual independent 1024^3 bf16 GEMMs: blocks 0-255 -> (A0,B0,C0), 256-511 -> (A1,B1,C1)
__global__ __launch_bounds__(256)
void gemm_dual_kernel(const unsigned short* A0, const unsigned short* B0, unsigned short* C0,
                      const unsigned short* A1, const unsigned short* B1, unsigned short* C1,
                      const float* cvx, unsigned short* cvxb, int cvt_base, int cvt_cnt)
{
  const int bid = blockIdx.x;
  if (bid >= 512) {
    convert_slice(cvx, cvxb, cvt_base, cvt_cnt, bid - 512, gridDim.x - 512);
    return;
  }
  const bool sec = bid >= 256;
  gemm_body<64, false, false>(sec ? A1 : A0, sec ? B1 : B0, sec ? (void*)C1 : (void*)C0,
                              nullptr, 1024, 1024, 256, sec ? bid - 256 : bid);
}

// ---------- 3b) 256x256 4-phase GEMM (final): C = A @ B^T + bias, fp32 out ----------
// ROUND-3 VERBATIM (best measured: 87.5 us, MfmaUtil 32%, 0 bank conflicts).
template<int QI, int QJ>
__device__ __forceinline__ void phase_compute(const char* Ab, const char* Bb,
    int wm, int wn, int lr, int klo, int sw, f32x4 (&accq)[4][2])
{
  const char* Ah = Ab + QI * 16384;
  const char* Bh = Bb + QJ * 16384;
  #pragma unroll
  for (int ks = 0; ks < 2; ++ks) {
    const int cb = (ks * 64 + klo) ^ sw;
    bf16x8 av[4], bv[2];
    #pragma unroll
    for (int i = 0; i < 4; ++i) {
      const int ra = wm * 64 + i * 16 + lr;
      av[i] = *(const bf16x8*)(Ah + ra * 128 + cb);
    }
    #pragma unroll
    for (int j = 0; j < 2; ++j) {
      const int rb = wn * 32 + j * 16 + lr;
      bv[j] = *(const bf16x8*)(Bh + rb * 128 + cb);
    }
    __builtin_amdgcn_s_setprio(1);
    #pragma unroll
    for (int i = 0; i < 4; ++i)
      #pragma unroll
      for (int j = 0; j < 2; ++j)
        accq[i][j] = __builtin_amdgcn_mfma_f32_16x16x32_bf16(av[i], bv[j], accq[i][j], 0, 0, 0);
    __builtin_amdgcn_s_setprio(0);
  }
}

__global__ __launch_bounds__(512, 2)
void gemm256_kernel(const unsigned short* __restrict__ A,   // [M,K] bf16
                    const unsigned short* __restrict__ B,   // [N,K] bf16
                    float* __restrict__ C, const float* __restrict__ bias,
                    int N, int K)
{
  extern __shared__ __align__(16) char lds[];   // 131072 B
  const int tid = threadIdx.x;
  const int w = tid >> 6, l = tid & 63;
  const int wm = w >> 2, wn = w & 3;
  const int lr = l & 15;
  const int klo = (l >> 4) << 4;      // byte col of k-slot
  const int sw  = (lr & 7) << 4;      // read-side XOR swizzle

  const int nwg = gridDim.x;
  const int bid = blockIdx.x;
  const int cpx = nwg >> 3;
  const int swz = (bid & 7) * cpx + (bid >> 3);
  const int ntn = N >> 8;
  const int n0 = (swz % ntn) << 8;
  const int m0 = (swz / ntn) << 8;

  // staging source offsets (elements), inverse-swizzled global col
  unsigned int aoff[2][2], boff[2][2];
  #pragma unroll
  for (int q = 0; q < 2; ++q)
    #pragma unroll
    for (int it = 0; it < 2; ++it) {
      int L = it * 8192 + tid * 16;            // byte pos within half-tile
      int r = L >> 7;                          // row 0..127
      int cs = (L & 127) ^ ((r & 7) << 4);     // source col bytes (pre-swizzled)
      aoff[q][it] = (unsigned)(m0 + q * 128 + r) * K + (cs >> 1);
      boff[q][it] = (unsigned)(n0 + q * 128 + r) * K + (cs >> 1);
    }
  char* ldsA = lds;
  char* ldsB = lds + 65536;
  const int wdst = w * 1024;

#define STG_A(bufo, q, k0) do { \
    gload_lds16(A + aoff[q][0] + (k0), ldsA + (bufo) + (q) * 16384 + wdst); \
    gload_lds16(A + aoff[q][1] + (k0), ldsA + (bufo) + (q) * 16384 + 8192 + wdst); } while (0)
#define STG_B(bufo, q, k0) do { \
    gload_lds16(B + boff[q][0] + (k0), ldsB + (bufo) + (q) * 16384 + wdst); \
    gload_lds16(B + boff[q][1] + (k0), ldsB + (bufo) + (q) * 16384 + 8192 + wdst); } while (0)

  f32x4 acc[2][2][4][2] = {};

  // prologue: stage tile 0 into buf 0 (order A0,B0,B1,A1)
  STG_A(0, 0, 0); STG_B(0, 0, 0); STG_B(0, 1, 0); STG_A(0, 1, 0);

  const int NT = K >> 6;
  int curo = 0;
  for (int t = 0; t < NT - 1; ++t) {
    const int nxto = curo ^ 32768;
    const int k1 = (t + 1) << 6;
    STG_A(nxto, 0, k1);
    asm volatile("s_waitcnt vmcnt(6)" ::: "memory");
    LBAR();
    phase_compute<0, 0>(ldsA + curo, ldsB + curo, wm, wn, lr, klo, sw, acc[0][0]);
    STG_B(nxto, 0, k1);
    asm volatile("s_waitcnt vmcnt(6)" ::: "memory");
    LBAR();
    phase_compute<0, 1>(ldsA + curo, ldsB + curo, wm, wn, lr, klo, sw, acc[0][1]);
    STG_B(nxto, 1, k1);
    asm volatile("s_waitcnt vmcnt(6)" ::: "memory");
    LBAR();
    phase_compute<1, 0>(ldsA + curo, ldsB + curo, wm, wn, lr, klo, sw, acc[1][0]);
    STG_A(nxto, 1, k1);
    phase_compute<1, 1>(ldsA + curo, ldsB + curo, wm, wn, lr, klo, sw, acc[1][1]);
    curo = nxto;
  }
  asm volatile("s_waitcnt vmcnt(4)" ::: "memory");
  LBAR();
  phase_compute<0, 0>(ldsA + curo, ldsB + curo, wm, wn, lr, klo, sw, acc[0][0]);
  asm volatile("s_waitcnt vmcnt(2)" ::: "memory");
  LBAR();
  phase_compute<0, 1>(ldsA + curo, ldsB + curo, wm, wn, lr, klo, sw, acc[0][1]);
  asm volatile("s_waitcnt vmcnt(0)" ::: "memory");
  LBAR();
  phase_compute<1, 0>(ldsA + curo, ldsB + curo, wm, wn, lr, klo, sw, acc[1][0]);
  phase_compute<1, 1>(ldsA + curo, ldsB + curo, wm, wn, lr, klo, sw, acc[1][1]);

  // epilogue: C/D layout col = lane&15, row = (lane>>4)*4 + reg
  const int cr = (l >> 4) << 2;
  const int cc = l & 15;
  #pragma unroll
  for (int qi = 0; qi < 2; ++qi)
    #pragma unroll
    for (int qj = 0; qj < 2; ++qj)
      #pragma unroll
      for (int j = 0; j < 2; ++j) {
        const int col = n0 + qj * 128 + wn * 32 + j * 16 + cc;
        const float bv = bias[col];
        #pragma unroll
        for (int i = 0; i < 4; ++i) {
          const int rbase = m0 + qi * 128 + wm * 64 + i * 16 + cr;
          #pragma unroll
          for (int r = 0; r < 4; ++r)
            C[(size_t)(rbase + r) * N + col] = acc[qi][qj][i][j][r] + bv;
        }
      }
#undef STG_A
#undef STG_B
}

// ---------- launch ----------
// Tree compose: M = (S3·(B2 S2)) · (B1·(S1·(B0 S0)))
//   bd-dual:  T2=(B2 S2)^T -> t0 ; T0=(B0 S0)^T -> t1
//   gemm-dual: left = S3 @ T2^T -> s0 ; Yt = T0 @ S1^T = (S1·(B0 S0))^T -> s2
//   bdiag_right: Zt = Yt·B1-transform -> t1
//   G3: M = left @ Zt^T -> t0
extern "C" void kernel_launch(void* const* d_in, const int* in_sizes, int n_in,
                              void* d_out, int out_size, void* d_ws, size_t ws_size,
                              hipStream_t stream) {
  (void)in_sizes; (void)n_in; (void)out_size;
  const float* x    = (const float*)d_in[0];
  const float* P0   = (const float*)d_in[1];
  const float* P1   = (const float*)d_in[2];
  const float* P2   = (const float*)d_in[3];
  const float* P3   = (const float*)d_in[4];
  const float* K0   = (const float*)d_in[5];
  const float* K1   = (const float*)d_in[6];
  const float* K2   = (const float*)d_in[7];
  const float* bias = (const float*)d_in[8];

  unsigned short* S  = (unsigned short*)d_ws;
  unsigned short* s0 = S;
  unsigned short* s1 = S + (1u << 20);
  unsigned short* s2 = S + (2u << 20);
  unsigned short* s3 = S + (3u << 20);
  unsigned short* t0 = S + (4u << 20);
  unsigned short* t1 = S + (5u << 20);
  unsigned short* Xb = S + (6u << 20);
  const size_t need = ((size_t)6 * (1u << 20) + (size_t)32768 * 1024) * 2;
  const bool have_xb = ws_size >= need;
  unsigned short* xbp = have_xb ? Xb : nullptr;

  // convert distributed in 8 slices of 512K ushort8-groups across the 5 chain launches
  const int SL = 524288;
  const int cvt2 = have_xb ? 2 * SL : 0;
  const int cvt1 = have_xb ? SL : 0;
  const int tail_smx = have_xb ? 1024 : 0;
  const int tail_512 = have_xb ? 512 : 0;
  const int tail_256 = have_xb ? 256 : 0;

  // 1) softmax of all P (+2 cvt slices)
  softmax4_kernel<<<4096 + tail_smx, 256, 0, stream>>>(P0, P1, P2, P3, S, x, xbp, cvt2);

  // 2) both block-diag transposes (+2 slices): T2=(B2 S2)^T -> t0, T0=(B0 S0)^T -> t1
  blockdiagT_dual_kernel<<<256 + tail_512, 256, 0, stream>>>(K2, s2, t0, K0, s0, t1,
                                                             x, xbp, 2 * SL, cvt2);

  // 3) two independent 1024^3 GEMMs (+2 slices): left -> s0 ; Yt -> s2
  gemm_dual_kernel<<<512 + tail_512, 256, 0, stream>>>(s3, t0, s0, t1, s1, s2,
                                                       x, xbp, 4 * SL, cvt2);

  // 4) Zt = right-blockdiag(K1, Yt) -> t1  (+1 slice)
  bdiag_right_kernel<<<256 + tail_256, 256, 0, stream>>>(K1, s2, t1, x, xbp, 6 * SL, cvt1);

  // 5) M = left @ Zt^T -> t0  (+1 slice)
  gemm_bt_kernel<64, false, false><<<256 + tail_512, 256, 0, stream>>>((const void*)s0, t1,
      (void*)t0, nullptr, 1024, 1024, 256, x, xbp, 7 * SL, cvt1);

  // 6) final: out = Xb @ M^T + bias
  bool ok256 = false;
  if (have_xb) {
    hipError_t e = hipFuncSetAttribute((const void*)gemm256_kernel,
                                       hipFuncAttributeMaxDynamicSharedMemorySize, 131072);
    ok256 = (e == hipSuccess);
  }
  if (ok256) {
    gemm256_kernel<<<512, 512, 131072, stream>>>(Xb, t0, (float*)d_out, bias, 1024, 1024);
  } else if (have_xb) {
    gemm_bt_kernel<128, false, true><<<2048, 256, 0, stream>>>((const void*)Xb, t0,
        d_out, bias, 1024, 1024, 2048, nullptr, nullptr, 0, 0);
  } else {
    gemm_bt_kernel<128, true, true><<<2048, 256, 0, stream>>>((const void*)x, t0,
        d_out, bias, 1024, 1024, 2048, nullptr, nullptr, 0, 0);
  }
}

// Round 8
// 159.398 us; speedup vs baseline: 1.7432x; 1.0112x over previous
//
#include <hip/hip_runtime.h>
#include <hip/hip_bf16.h>

// ---------- helpers ----------
typedef __bf16 bf16x8 __attribute__((ext_vector_type(8)));
typedef float f32x4 __attribute__((ext_vector_type(4)));
typedef unsigned short u16x8 __attribute__((ext_vector_type(8)));

__device__ __forceinline__ unsigned short f2bf(float f) {
  unsigned u = __float_as_uint(f);
  u += 0x7FFF + ((u >> 16) & 1);          // RNE
  return (unsigned short)(u >> 16);
}
__device__ __forceinline__ float bf2f(unsigned short h) {
  return __uint_as_float((unsigned)h << 16);
}

__device__ __forceinline__ void gload_lds16(const void* g, void* l) {
  __builtin_amdgcn_global_load_lds(
      (const __attribute__((address_space(1))) void*)g,
      (__attribute__((address_space(3))) void*)l, 16, 0, 0);
}

#define LBAR() do { asm volatile("s_waitcnt lgkmcnt(0)" ::: "memory"); \
                    __builtin_amdgcn_s_barrier(); } while (0)

// grid-strided fp32->bf16 convert slice, run by tail blocks of latency-bound launches
__device__ __forceinline__ void convert_slice(const float* __restrict__ x,
                                              unsigned short* __restrict__ xb,
                                              int base8, int cnt8, int cb, int nb)
{
  int i = cb * 256 + (int)threadIdx.x;
  const int stride = nb * 256;
  for (; i < cnt8; i += stride) {
    const size_t g = (size_t)(base8 + i);
    float4 v0 = ((const float4*)x)[2 * g];
    float4 v1 = ((const float4*)x)[2 * g + 1];
    u16x8 uv;
    uv[0] = f2bf(v0.x); uv[1] = f2bf(v0.y); uv[2] = f2bf(v0.z); uv[3] = f2bf(v0.w);
    uv[4] = f2bf(v1.x); uv[5] = f2bf(v1.y); uv[6] = f2bf(v1.z); uv[7] = f2bf(v1.w);
    ((u16x8*)xb)[g] = uv;
  }
}

// ---------- 1) row softmax of 4 P matrices -> bf16 (+ convert tail blocks) ----------
__global__ __launch_bounds__(256)
void softmax4_kernel(const float* __restrict__ P0, const float* __restrict__ P1,
                     const float* __restrict__ P2, const float* __restrict__ P3,
                     unsigned short* __restrict__ S,
                     const float* __restrict__ cvx, unsigned short* __restrict__ cvxb,
                     int cvt_cnt)
{
  if (blockIdx.x >= 4096) {
    convert_slice(cvx, cvxb, 0, cvt_cnt, blockIdx.x - 4096, gridDim.x - 4096);
    return;
  }
  const int bid = blockIdx.x;
  const int mat = bid >> 10, row = bid & 1023;
  const float* P = (mat == 0 ? P0 : mat == 1 ? P1 : mat == 2 ? P2 : P3) + (size_t)row * 1024;
  unsigned short* out = S + ((size_t)mat << 20) + (size_t)row * 1024;
  const int t = threadIdx.x, w = t >> 6, l = t & 63;
  float4 v = ((const float4*)P)[t];
  float mx = fmaxf(fmaxf(v.x, v.y), fmaxf(v.z, v.w));
  #pragma unroll
  for (int off = 32; off > 0; off >>= 1) mx = fmaxf(mx, __shfl_xor(mx, off));
  __shared__ float redA[4], redB[4];
  if (l == 0) redA[w] = mx;
  __syncthreads();
  mx = fmaxf(fmaxf(redA[0], redA[1]), fmaxf(redA[2], redA[3]));
  float e0 = __expf(v.x - mx), e1 = __expf(v.y - mx);
  float e2 = __expf(v.z - mx), e3 = __expf(v.w - mx);
  float s = e0 + e1 + e2 + e3;
  #pragma unroll
  for (int off = 32; off > 0; off >>= 1) s += __shfl_xor(s, off);
  if (l == 0) redB[w] = s;
  __syncthreads();
  s = redB[0] + redB[1] + redB[2] + redB[3];
  float inv = 1.0f / s;
  ushort4 o;
  o.x = f2bf(e0 * inv); o.y = f2bf(e1 * inv);
  o.z = f2bf(e2 * inv); o.w = f2bf(e3 * inv);
  ((ushort4*)out)[t] = o;
}

// ---------- 2) blockdiagT body: outT = ((blockdiag(K))^T @ in)^T ----------
__device__ __forceinline__ void bdT_body(const float* __restrict__ Kb,
                                         const unsigned short* __restrict__ in,
                                         unsigned short* __restrict__ outT, int bid)
{
  const int n = bid >> 2;
  const int c = (bid & 3) * 256 + threadIdx.x;
  __shared__ float Ks[32][33];
  for (int t = threadIdx.x; t < 1024; t += 256)
    Ks[t >> 5][t & 31] = Kb[n * 1024 + t];
  __syncthreads();
  float ri[32];
  #pragma unroll
  for (int i = 0; i < 32; ++i)
    ri[i] = bf2f(in[(size_t)(n * 32 + i) * 1024 + c]);
  unsigned short ov[32];
  #pragma unroll
  for (int o = 0; o < 32; ++o) {
    float acc = 0.f;
    #pragma unroll
    for (int i = 0; i < 32; ++i) acc = fmaf(Ks[i][o], ri[i], acc);
    ov[o] = f2bf(acc);
  }
  u16x8* dst = (u16x8*)(outT + (size_t)c * 1024 + n * 32);
  const u16x8* src = (const u16x8*)ov;
  #pragma unroll
  for (int q = 0; q < 4; ++q) dst[q] = src[q];
}

// dual: blocks 0-127 -> (Ka,ina,outa), 128-255 -> (Kb2,inb,outb), >=256 convert
__global__ __launch_bounds__(256)
void blockdiagT_dual_kernel(const float* Ka, const unsigned short* ina, unsigned short* outa,
                            const float* Kb2, const unsigned short* inb, unsigned short* outb,
                            const float* cvx, unsigned short* cvxb, int cvt_base, int cvt_cnt)
{
  const int bid = blockIdx.x;
  if (bid >= 256) {
    convert_slice(cvx, cvxb, cvt_base, cvt_cnt, bid - 256, gridDim.x - 256);
    return;
  }
  const bool sec = bid >= 128;
  bdT_body(sec ? Kb2 : Ka, sec ? inb : ina, sec ? outb : outa, sec ? bid - 128 : bid);
}

// ---------- 2b) right-blockdiag: Zt[c, n*32+i] = sum_o Yt[c, n*32+o] * K[n][o][i] ----------
__global__ __launch_bounds__(256)
void bdiag_right_kernel(const float* __restrict__ Kb, const unsigned short* __restrict__ Yt,
                        unsigned short* __restrict__ Zt,
                        const float* cvx, unsigned short* cvxb, int cvt_base, int cvt_cnt)
{
  const int bid = blockIdx.x;
  if (bid >= 256) {
    convert_slice(cvx, cvxb, cvt_base, cvt_cnt, bid - 256, gridDim.x - 256);
    return;
  }
  const int n = bid & 31, rowg = bid >> 5;
  __shared__ float Ks[32][32];   // Ks[o][i]
  for (int t = threadIdx.x; t < 1024; t += 256)
    Ks[t >> 5][t & 31] = Kb[n * 1024 + t];
  __syncthreads();
  const int row = rowg * 128 + ((int)threadIdx.x >> 1);
  const int ih = ((int)threadIdx.x & 1) * 16;
  const unsigned short* yrow = Yt + (size_t)row * 1024 + n * 32;
  float y[32];
  #pragma unroll
  for (int q = 0; q < 4; ++q) {
    u16x8 v = ((const u16x8*)yrow)[q];
    #pragma unroll
    for (int e = 0; e < 8; ++e) y[q * 8 + e] = bf2f(v[e]);
  }
  float acc[16] = {};
  #pragma unroll
  for (int o = 0; o < 32; ++o)
    #pragma unroll
    for (int ii = 0; ii < 16; ++ii)
      acc[ii] = fmaf(y[o], Ks[o][ih + ii], acc[ii]);
  u16x8 ov[2];
  #pragma unroll
  for (int ii = 0; ii < 16; ++ii) ov[ii >> 3][ii & 7] = f2bf(acc[ii]);
  u16x8* dst = (u16x8*)(Zt + (size_t)row * 1024 + n * 32 + ih);
  dst[0] = ov[0]; dst[1] = ov[1];
}

// ---------- 3a) 2-barrier GEMM body (compose chain + fallback): C = A @ B^T ----------
template<int TILE, bool A_FP32, bool OUT_BIAS>
__device__ __forceinline__ void gemm_body(const void* __restrict__ Av,
                                          const unsigned short* __restrict__ B,
                                          void* __restrict__ Cv, const float* __restrict__ bias,
                                          int N, int K, int nprim, int bid)
{
  constexpr int FR  = TILE / 32;
  constexpr int SIT = TILE / 32;
  __shared__ unsigned short Asm[TILE * 64];
  __shared__ unsigned short Bsm[TILE * 64];
  const int tid = threadIdx.x;
  const int w = tid >> 6, l = tid & 63;
  const int cpx = nprim >> 3;
  const int swz = (bid & 7) * cpx + (bid >> 3);
  const int ntn = N / TILE;
  const int n0 = (swz % ntn) * TILE;
  const int m0 = (swz / ntn) * TILE;
  const int wr = (w >> 1) * (TILE / 2), wc = (w & 1) * (TILE / 2);
  const int lr = l & 15, kg = (l >> 4) << 3;

  f32x4 acc[FR][FR] = {};
  const int KT = K >> 6;
  for (int kt = 0; kt < KT; ++kt) {
    const int k0 = kt << 6;
    if (kt) __syncthreads();
    #pragma unroll
    for (int it = 0; it < SIT; ++it) {
      int li = it * 256 + tid;
      int row = li >> 3, c8 = (li & 7) << 3;
      const unsigned short* g = B + (size_t)(n0 + row) * K + (k0 + c8);
      gload_lds16(g, (char*)Bsm + it * 4096 + w * 1024);
    }
    if (A_FP32) {
      const float* Af = (const float*)Av;
      #pragma unroll
      for (int p = 0; p < SIT; ++p) {
        int row = (tid >> 3) + p * 32;
        int c8 = (tid & 7) << 3;
        const float* g = Af + (size_t)(m0 + row) * K + (k0 + c8);
        float4 v0 = ((const float4*)g)[0];
        float4 v1 = ((const float4*)g)[1];
        u16x8 uv;
        uv[0] = f2bf(v0.x); uv[1] = f2bf(v0.y); uv[2] = f2bf(v0.z); uv[3] = f2bf(v0.w);
        uv[4] = f2bf(v1.x); uv[5] = f2bf(v1.y); uv[6] = f2bf(v1.z); uv[7] = f2bf(v1.w);
        *(u16x8*)&Asm[row * 64 + c8] = uv;
      }
    } else {
      const unsigned short* Ab = (const unsigned short*)Av;
      #pragma unroll
      for (int it = 0; it < SIT; ++it) {
        int li = it * 256 + tid;
        int row = li >> 3, c8 = (li & 7) << 3;
        const unsigned short* g = Ab + (size_t)(m0 + row) * K + (k0 + c8);
        gload_lds16(g, (char*)Asm + it * 4096 + w * 1024);
      }
    }
    __syncthreads();
    #pragma unroll
    for (int ks = 0; ks < 2; ++ks) {
      const int kb = ks * 32 + kg;
      bf16x8 af[FR], bfr[FR];
      #pragma unroll
      for (int i = 0; i < FR; ++i)
        af[i] = *(const bf16x8*)&Asm[(wr + i * 16 + lr) * 64 + kb];
      #pragma unroll
      for (int j = 0; j < FR; ++j)
        bfr[j] = *(const bf16x8*)&Bsm[(wc + j * 16 + lr) * 64 + kb];
      #pragma unroll
      for (int i = 0; i < FR; ++i)
        #pragma unroll
        for (int j = 0; j < FR; ++j)
          acc[i][j] = __builtin_amdgcn_mfma_f32_16x16x32_bf16(af[i], bfr[j], acc[i][j], 0, 0, 0);
    }
  }
  const int cr = (l >> 4) << 2;
  const int cc = l & 15;
  if (OUT_BIAS) {
    float* C = (float*)Cv;
    #pragma unroll
    for (int j = 0; j < FR; ++j) {
      int col = n0 + wc + j * 16 + cc;
      float bv = bias[col];
      #pragma unroll
      for (int i = 0; i < FR; ++i) {
        int rbase = m0 + wr + i * 16 + cr;
        #pragma unroll
        for (int r = 0; r < 4; ++r)
          C[(size_t)(rbase + r) * N + col] = acc[i][j][r] + bv;
      }
    }
  } else {
    unsigned short* C = (unsigned short*)Cv;
    #pragma unroll
    for (int j = 0; j < FR; ++j) {
      int col = n0 + wc + j * 16 + cc;
      #pragma unroll
      for (int i = 0; i < FR; ++i) {
        int rbase = m0 + wr + i * 16 + cr;
        #pragma unroll
        for (int r = 0; r < 4; ++r)
          C[(size_t)(rbase + r) * N + col] = f2bf(acc[i][j][r]);
      }
    }
  }
}

template<int TILE, bool A_FP32, bool OUT_BIAS>
__global__ __launch_bounds__(256)
void gemm_bt_kernel(const void* __restrict__ Av, const unsigned short* __restrict__ B,
                    void* __restrict__ Cv, const float* __restrict__ bias,
                    int N, int K, int nprim,
                    const float* cvx, unsigned short* cvxb, int cvt_base, int cvt_cnt)
{
  if ((int)blockIdx.x >= nprim) {
    convert_slice(cvx, cvxb, cvt_base, cvt_cnt, blockIdx.x - nprim, gridDim.x - nprim);
    return;
  }
  gemm_body<TILE, A_FP32, OUT_BIAS>(Av, B, Cv, bias, N, K, nprim, blockIdx.x);
}

// dual independent 1024^3 bf16 GEMMs: blocks 0-255 -> (A0,B0,C0), 256-511 -> (A1,B1,C1)
__global__ __launch_bounds__(256)
void gemm_dual_kernel(const unsigned short* A0, const unsigned short* B0, unsigned short* C0,
                      const unsigned short* A1, const unsigned short* B1, unsigned short* C1,
                      const float* cvx, unsigned short* cvxb, int cvt_base, int cvt_cnt)
{
  const int bid = blockIdx.x;
  if (bid >= 512) {
    convert_slice(cvx, cvxb, cvt_base, cvt_cnt, bid - 512, gridDim.x - 512);
    return;
  }
  const bool sec = bid >= 256;
  gemm_body<64, false, false>(sec ? A1 : A0, sec ? B1 : B0, sec ? (void*)C1 : (void*)C0,
                              nullptr, 1024, 1024, 256, sec ? bid - 256 : bid);
}

// ---------- 3b) 256x256 2-phase GEMM (final): C = A @ B^T + bias, fp32 out ----------
// Derived from ROUND-3 (counted-vmcnt, 16x16x32, XOR swizzle, 0 conflicts) with the
// two qj-phases MERGED: per K-tile 2 phases (qi=0,1). B frags (both halves, 8 reads)
// loaded once in phase 0, held in 16 VGPR, reused in phase 1. Per-wave ds_reads/tile:
// 48 -> 24 (minimum at this partition). Queue accounting (2 loads per STG):
//   prologue: A0,B0,B1,A1 (8 loads in flight)
//   t ph0: +A0',B0' (12) -> vmcnt(6) drains A0,B0,B1 of tile t ✓
//   t ph1: +B1',A1' (10) -> vmcnt(8) drains A1 of tile t ✓ -> 8 in flight (tile t+1)
//   last tile: vmcnt(2) / vmcnt(0).
// Race-freedom: t+1 ph0 stores target halves {A0,B0} of the buffer whose only reads
// still possibly pending are A1 (t ph1) - disjoint; t+1 ph1 stores happen after the
// t+1 ph0 barrier, by which every wave's t ph1 ds_reads completed (lgkmcnt0+barrier).
template<int QI>
__device__ __forceinline__ void phase_merged(const char* ldsAc, const char* ldsBc,
    int wm, int wn, int lr, int klo, int sw,
    bf16x8 (&bv)[2][2][2], f32x4 (&accq)[2][4][2])
{
  const char* Ah = ldsAc + QI * 16384;
  if (QI == 0) {
    #pragma unroll
    for (int qj = 0; qj < 2; ++qj) {
      const char* Bh = ldsBc + qj * 16384;
      #pragma unroll
      for (int ks = 0; ks < 2; ++ks) {
        const int cb = (ks * 64 + klo) ^ sw;
        #pragma unroll
        for (int j = 0; j < 2; ++j)
          bv[qj][j][ks] = *(const bf16x8*)(Bh + (wn * 32 + j * 16 + lr) * 128 + cb);
      }
    }
  }
  #pragma unroll
  for (int ks = 0; ks < 2; ++ks) {
    const int cb = (ks * 64 + klo) ^ sw;
    bf16x8 av[4];
    #pragma unroll
    for (int i = 0; i < 4; ++i)
      av[i] = *(const bf16x8*)(Ah + (wm * 64 + i * 16 + lr) * 128 + cb);
    __builtin_amdgcn_s_setprio(1);
    #pragma unroll
    for (int i = 0; i < 4; ++i)
      #pragma unroll
      for (int qj = 0; qj < 2; ++qj)
        #pragma unroll
        for (int j = 0; j < 2; ++j)
          accq[qj][i][j] = __builtin_amdgcn_mfma_f32_16x16x32_bf16(av[i], bv[qj][j][ks],
                                                                  accq[qj][i][j], 0, 0, 0);
    __builtin_amdgcn_s_setprio(0);
  }
}

__global__ __launch_bounds__(512, 2)
void gemm256_kernel(const unsigned short* __restrict__ A,   // [M,K] bf16
                    const unsigned short* __restrict__ B,   // [N,K] bf16
                    float* __restrict__ C, const float* __restrict__ bias,
                    int N, int K)
{
  extern __shared__ __align__(16) char lds[];   // 131072 B
  const int tid = threadIdx.x;
  const int w = tid >> 6, l = tid & 63;
  const int wm = w >> 2, wn = w & 3;
  const int lr = l & 15;
  const int klo = (l >> 4) << 4;      // byte col of k-slot
  const int sw  = (lr & 7) << 4;      // read-side XOR swizzle

  const int nwg = gridDim.x;
  const int bid = blockIdx.x;
  const int cpx = nwg >> 3;
  const int swz = (bid & 7) * cpx + (bid >> 3);
  const int ntn = N >> 8;
  const int n0 = (swz % ntn) << 8;
  const int m0 = (swz / ntn) << 8;

  // staging source offsets (elements), inverse-swizzled global col
  unsigned int aoff[2][2], boff[2][2];
  #pragma unroll
  for (int q = 0; q < 2; ++q)
    #pragma unroll
    for (int it = 0; it < 2; ++it) {
      int L = it * 8192 + tid * 16;            // byte pos within half-tile
      int r = L >> 7;                          // row 0..127
      int cs = (L & 127) ^ ((r & 7) << 4);     // source col bytes (pre-swizzled)
      aoff[q][it] = (unsigned)(m0 + q * 128 + r) * K + (cs >> 1);
      boff[q][it] = (unsigned)(n0 + q * 128 + r) * K + (cs >> 1);
    }
  char* ldsA = lds;
  char* ldsB = lds + 65536;
  const int wdst = w * 1024;

#define STG_A(bufo, q, k0) do { \
    gload_lds16(A + aoff[q][0] + (k0), ldsA + (bufo) + (q) * 16384 + wdst); \
    gload_lds16(A + aoff[q][1] + (k0), ldsA + (bufo) + (q) * 16384 + 8192 + wdst); } while (0)
#define STG_B(bufo, q, k0) do { \
    gload_lds16(B + boff[q][0] + (k0), ldsB + (bufo) + (q) * 16384 + wdst); \
    gload_lds16(B + boff[q][1] + (k0), ldsB + (bufo) + (q) * 16384 + 8192 + wdst); } while (0)

  f32x4 acc[2][2][4][2] = {};   // [qi][qj][i][j]
  bf16x8 bv[2][2][2];           // [qj][j][ks], loaded in ph0, reused in ph1

  // prologue: stage tile 0 into buf 0 (order A0,B0,B1,A1)
  STG_A(0, 0, 0); STG_B(0, 0, 0); STG_B(0, 1, 0); STG_A(0, 1, 0);

  const int NT = K >> 6;
  int curo = 0;
  for (int t = 0; t < NT - 1; ++t) {
    const int nxto = curo ^ 32768;
    const int k1 = (t + 1) << 6;
    // phase 0: compute qi=0 (both qj); stage next A0,B0; drain cur A0,B0,B1
    STG_A(nxto, 0, k1); STG_B(nxto, 0, k1);
    asm volatile("s_waitcnt vmcnt(6)" ::: "memory");
    LBAR();
    phase_merged<0>(ldsA + curo, ldsB + curo, wm, wn, lr, klo, sw, bv, acc[0]);
    // phase 1: compute qi=1 (B from regs); stage next B1,A1; drain cur A1
    STG_B(nxto, 1, k1); STG_A(nxto, 1, k1);
    asm volatile("s_waitcnt vmcnt(8)" ::: "memory");
    LBAR();
    phase_merged<1>(ldsA + curo, ldsB + curo, wm, wn, lr, klo, sw, bv, acc[1]);
    curo = nxto;
  }
  // last tile: no staging, drain 2 -> 0
  asm volatile("s_waitcnt vmcnt(2)" ::: "memory");
  LBAR();
  phase_merged<0>(ldsA + curo, ldsB + curo, wm, wn, lr, klo, sw, bv, acc[0]);
  asm volatile("s_waitcnt vmcnt(0)" ::: "memory");
  LBAR();
  phase_merged<1>(ldsA + curo, ldsB + curo, wm, wn, lr, klo, sw, bv, acc[1]);

  // epilogue: C/D layout col = lane&15, row = (lane>>4)*4 + reg
  const int cr = (l >> 4) << 2;
  const int cc = l & 15;
  #pragma unroll
  for (int qi = 0; qi < 2; ++qi)
    #pragma unroll
    for (int qj = 0; qj < 2; ++qj)
      #pragma unroll
      for (int j = 0; j < 2; ++j) {
        const int col = n0 + qj * 128 + wn * 32 + j * 16 + cc;
        const float bvv = bias[col];
        #pragma unroll
        for (int i = 0; i < 4; ++i) {
          const int rbase = m0 + qi * 128 + wm * 64 + i * 16 + cr;
          #pragma unroll
          for (int r = 0; r < 4; ++r)
            C[(size_t)(rbase + r) * N + col] = acc[qi][qj][i][j][r] + bvv;
        }
      }
#undef STG_A
#undef STG_B
}

// ---------- launch ----------
// Tree compose: M = (S3·(B2 S2)) · (B1·(S1·(B0 S0)))
//   bd-dual:  T2=(B2 S2)^T -> t0 ; T0=(B0 S0)^T -> t1
//   gemm-dual: left = S3 @ T2^T -> s0 ; Yt = T0 @ S1^T = (S1·(B0 S0))^T -> s2
//   bdiag_right: Zt = Yt·B1-transform -> t1
//   G3: M = left @ Zt^T -> t0
extern "C" void kernel_launch(void* const* d_in, const int* in_sizes, int n_in,
                              void* d_out, int out_size, void* d_ws, size_t ws_size,
                              hipStream_t stream) {
  (void)in_sizes; (void)n_in; (void)out_size;
  const float* x    = (const float*)d_in[0];
  const float* P0   = (const float*)d_in[1];
  const float* P1   = (const float*)d_in[2];
  const float* P2   = (const float*)d_in[3];
  const float* P3   = (const float*)d_in[4];
  const float* K0   = (const float*)d_in[5];
  const float* K1   = (const float*)d_in[6];
  const float* K2   = (const float*)d_in[7];
  const float* bias = (const float*)d_in[8];

  unsigned short* S  = (unsigned short*)d_ws;
  unsigned short* s0 = S;
  unsigned short* s1 = S + (1u << 20);
  unsigned short* s2 = S + (2u << 20);
  unsigned short* s3 = S + (3u << 20);
  unsigned short* t0 = S + (4u << 20);
  unsigned short* t1 = S + (5u << 20);
  unsigned short* Xb = S + (6u << 20);
  const size_t need = ((size_t)6 * (1u << 20) + (size_t)32768 * 1024) * 2;
  const bool have_xb = ws_size >= need;
  unsigned short* xbp = have_xb ? Xb : nullptr;

  // convert distributed in 8 slices of 512K ushort8-groups across the 5 chain launches
  const int SL = 524288;
  const int cvt2 = have_xb ? 2 * SL : 0;
  const int cvt1 = have_xb ? SL : 0;
  const int tail_smx = have_xb ? 1024 : 0;
  const int tail_512 = have_xb ? 512 : 0;
  const int tail_256 = have_xb ? 256 : 0;

  // 1) softmax of all P (+2 cvt slices)
  softmax4_kernel<<<4096 + tail_smx, 256, 0, stream>>>(P0, P1, P2, P3, S, x, xbp, cvt2);

  // 2) both block-diag transposes (+2 slices): T2=(B2 S2)^T -> t0, T0=(B0 S0)^T -> t1
  blockdiagT_dual_kernel<<<256 + tail_512, 256, 0, stream>>>(K2, s2, t0, K0, s0, t1,
                                                             x, xbp, 2 * SL, cvt2);

  // 3) two independent 1024^3 GEMMs (+2 slices): left -> s0 ; Yt -> s2
  gemm_dual_kernel<<<512 + tail_512, 256, 0, stream>>>(s3, t0, s0, t1, s1, s2,
                                                       x, xbp, 4 * SL, cvt2);

  // 4) Zt = right-blockdiag(K1, Yt) -> t1  (+1 slice)
  bdiag_right_kernel<<<256 + tail_256, 256, 0, stream>>>(K1, s2, t1, x, xbp, 6 * SL, cvt1);

  // 5) M = left @ Zt^T -> t0  (+1 slice)
  gemm_bt_kernel<64, false, false><<<256 + tail_512, 256, 0, stream>>>((const void*)s0, t1,
      (void*)t0, nullptr, 1024, 1024, 256, x, xbp, 7 * SL, cvt1);

  // 6) final: out = Xb @ M^T + bias
  bool ok256 = false;
  if (have_xb) {
    hipError_t e = hipFuncSetAttribute((const void*)gemm256_kernel,
                                       hipFuncAttributeMaxDynamicSharedMemorySize, 131072);
    ok256 = (e == hipSuccess);
  }
  if (ok256) {
    gemm256_kernel<<<512, 512, 131072, stream>>>(Xb, t0, (float*)d_out, bias, 1024, 1024);
  } else if (have_xb) {
    gemm_bt_kernel<128, false, true><<<2048, 256, 0, stream>>>((const void*)Xb, t0,
        d_out, bias, 1024, 1024, 2048, nullptr, nullptr, 0, 0);
  } else {
    gemm_bt_kernel<128, true, true><<<2048, 256, 0, stream>>>((const void*)x, t0,
        d_out, bias, 1024, 1024, 2048, nullptr, nullptr, 0, 0);
  }
}